// Round 12
// baseline (483.792 us; speedup 1.0000x reference)
//
#include <hip/hip_runtime.h>
#include <hip/hip_bf16.h>
#include <math.h>
#include <stdio.h>

#define HEADS 10
#define CH 78
#define F 780          // HEADS*CH
#define NGRAPH 512
#define NEG 0.2f
#define LOG2E 1.44269504f
#define KPAD 832       // GCN GEMM K: 780 padded to mult of 64
#define NPAD 896       // GCN GEMM N: 780 padded to mult of 128
#define K1 128         // transform GEMM K: 78 padded to mult of 64
#define N1 1560        // transform GEMM N: 780 (xl) + 780 (xr)
#define N1PAD 1664     // 1560 padded to mult of 128
#define K2PAD 1600     // FC1 K: 1560 padded to mult of 64
#define N2PAD 1536     // FC1 N: 1500 padded to mult of 128 (also FC2 K with zero pad)

typedef __attribute__((ext_vector_type(8))) short short8;
typedef __attribute__((ext_vector_type(4))) float f32x4;
typedef __fp16 __attribute__((ext_vector_type(2))) h2;   // packed fp16 pair (VOP3P)

__device__ inline void bf2unpack(unsigned int u, float& lo, float& hi) {
  union { unsigned int ui; float f; } a, b;
  a.ui = u << 16;
  b.ui = u & 0xffff0000u;
  lo = a.f; hi = b.f;
}

// VALU-pipe cross-lane add via DPP (dep latency ~4-8cy vs ds_swizzle ~30cy).
#define DPP_ADDF(v, ctrl)                                                      \
  ((v) + __builtin_bit_cast(float, __builtin_amdgcn_update_dpp(                \
             0, __builtin_bit_cast(int, (v)), ctrl, 0xF, 0xF, true)))

// xor16 within each 32-lane group. NOTE: permlane16_swap(p,p) is UNSAFE here —
// same-value operands can be allocated to one physical register, making the HW
// swap self-referential (round-6 correctness regression). Keep the shuffle.
__device__ inline float xor16_sum(float p) { return p + __shfl_xor(p, 16, 32); }

// raw 2^x (att is pre-scaled by log2e, so no v_mul needed)
#if __has_builtin(__builtin_amdgcn_exp2f)
#define EXP2F(x) __builtin_amdgcn_exp2f(x)
#else
#define EXP2F(x) exp2f(x)
#endif

// ---------------- merged preprocessing: casts + out init + EDGE COUNTING ----------
// counts must be pre-zeroed (hipMemsetAsync); self-loop +1 is applied in scan_k.
__global__ __launch_bounds__(256) void prep_k(const float* __restrict__ x,
                                              const float* __restrict__ Wl,
                                              const float* __restrict__ Wr,
                                              const float* __restrict__ Wgcn,
                                              const float* __restrict__ Wfc1,
                                              const float* __restrict__ Wfc2,
                                              const float* __restrict__ bfc2,
                                              const int* __restrict__ dstv,
                                              __hip_bfloat16* __restrict__ xb,
                                              __hip_bfloat16* __restrict__ Wlrb,
                                              __hip_bfloat16* __restrict__ Wtb,
                                              __hip_bfloat16* __restrict__ Wfc1b,
                                              __hip_bfloat16* __restrict__ Wfc2b,
                                              float* __restrict__ outinit,
                                              int* __restrict__ counts, int Nn, int E) {
  int i = blockIdx.x * 256 + threadIdx.x;
  int s0 = Nn * K1;
  int s1 = s0 + N1PAD * K1;
  int s2 = s1 + NPAD * KPAD;
  int s3 = s2 + N2PAD * K2PAD;
  int s4 = s3 + 128 * N2PAD;
  int s5 = s4 + NGRAPH * 128;
  int s6 = s5 + E;
  if (i < s0) {
    int row = i / K1, k = i - row * K1;
    xb[i] = __float2bfloat16((k < 78) ? x[(size_t)row * 78 + k] : 0.f);
  } else if (i < s1) {
    int j = i - s0;
    int n = j / K1, k = j - n * K1;
    float v = 0.f;
    if (k < 78 && n < N1) v = (n < F) ? Wl[(size_t)k * F + n] : Wr[(size_t)k * F + (n - F)];
    Wlrb[j] = __float2bfloat16(v);
  } else if (i < s2) {
    int j = i - s1;
    int n = j / KPAD, k = j - n * KPAD;
    float v = (n < F && k < F) ? Wgcn[(size_t)k * F + n] : 0.f;
    Wtb[j] = __float2bfloat16(v);
  } else if (i < s3) {
    int j = i - s2;
    int n = j / K2PAD, k = j - n * K2PAD;
    float v = (n < 1500 && k < 1560) ? Wfc1[(size_t)k * 1500 + n] : 0.f;
    Wfc1b[j] = __float2bfloat16(v);
  } else if (i < s4) {
    int j = i - s3;
    int n = j / N2PAD, k = j - n * N2PAD;     // n: out col 0..127, k: 0..1535
    float v = (k < 1500) ? Wfc2[(size_t)k * 128 + n] : 0.f;
    Wfc2b[j] = __float2bfloat16(v);
  } else if (i < s5) {
    int j = i - s4;
    outinit[j] = bfc2[j & 127];
  } else if (i < s6) {
    atomicAdd(&counts[dstv[i - s5]], 1);   // edge counting (counts pre-zeroed)
  }
}

// ---------------- bf16 MFMA GEMM core, BK=64 ----------------
__device__ inline void gl_lds16(const unsigned short* g, unsigned short* l) {
  __builtin_amdgcn_global_load_lds(
      (const __attribute__((address_space(1))) unsigned int*)g,
      (__attribute__((address_space(3))) unsigned int*)l, 16, 0, 0);
}

// A: [M][lda] bf16 row-major, Bt: [Ncols_pad][lda] bf16 (B transposed). K mult of 64.
// 128x128 tile, 4 waves x (4x4) mfma_f32_16x16x32_bf16.
// XCD-aware block swizzle (applied when gridDim.y % 8 == 0): all x-blocks that
// share one 128-row A-panel land on the SAME XCD (wg->XCD round-robins linear id),
// so the panel is fetched from HBM once per panel instead of once per x-block.
// Bijective: by = (lid&7) + 8*((lid>>3)/gx); bx = (lid>>3)%gx.
#define MFMA_CORE64(A, Bt, lda, K)                                                \
  __shared__ unsigned short As[128 * 64];                                         \
  __shared__ unsigned short Bs[128 * 64];                                         \
  int tid = threadIdx.x;                                                          \
  int wave = tid >> 6, lane = tid & 63;                                           \
  int bx_ = blockIdx.x, by_ = blockIdx.y;                                         \
  { int gx = gridDim.x, gy = gridDim.y;                                           \
    if ((gy & 7) == 0) {                                                          \
      int lid = by_ * gx + bx_;                                                   \
      int c = lid & 7, s = lid >> 3;                                              \
      int yg = s / gx;                                                            \
      by_ = c + 8 * yg;                                                           \
      bx_ = s - yg * gx;                                                          \
    } }                                                                           \
  int m0 = by_ * 128, n0 = bx_ * 128;                                             \
  int wr = (wave >> 1) * 64, wc = (wave & 1) * 64;                                \
  f32x4 acc[4][4];                                                                \
  _Pragma("unroll")                                                               \
  for (int i = 0; i < 4; ++i)                                                     \
    _Pragma("unroll")                                                             \
    for (int j = 0; j < 4; ++j) acc[i][j] = (f32x4){0.f, 0.f, 0.f, 0.f};          \
  int lrow = lane >> 3;                                                           \
  int lcol = (lane & 7) * 8;                                                      \
  const unsigned short* gA0 = A + (size_t)(m0 + wave * 32 + lrow) * lda + lcol;   \
  const unsigned short* gB0 = Bt + (size_t)(n0 + wave * 32 + lrow) * lda + lcol;  \
  unsigned short* lA = As + (wave * 32) * 64;                                     \
  unsigned short* lB = Bs + (wave * 32) * 64;                                     \
  int q8 = (lane >> 4) * 8;                                                       \
  int fr = lane & 15;                                                             \
  for (int k0 = 0; k0 < K; k0 += 64) {                                            \
    _Pragma("unroll")                                                             \
    for (int c = 0; c < 4; ++c) {                                                 \
      gl_lds16(gA0 + (size_t)(8 * c) * lda, lA + (8 * c) * 64);                   \
      gl_lds16(gB0 + (size_t)(8 * c) * lda, lB + (8 * c) * 64);                   \
    }                                                                             \
    gA0 += 64; gB0 += 64;                                                         \
    __syncthreads();                                                              \
    _Pragma("unroll")                                                             \
    for (int ks = 0; ks < 64; ks += 32) {                                         \
      short8 a[4], b[4];                                                          \
      _Pragma("unroll")                                                           \
      for (int i = 0; i < 4; ++i) a[i] = *(const short8*)&As[(wr + 16 * i + fr) * 64 + ks + q8]; \
      _Pragma("unroll")                                                           \
      for (int j = 0; j < 4; ++j) b[j] = *(const short8*)&Bs[(wc + 16 * j + fr) * 64 + ks + q8]; \
      _Pragma("unroll")                                                           \
      for (int i = 0; i < 4; ++i)                                                 \
        _Pragma("unroll")                                                         \
        for (int j = 0; j < 4; ++j)                                               \
          acc[i][j] = __builtin_amdgcn_mfma_f32_16x16x32_bf16(a[i], b[j], acc[i][j], 0, 0, 0); \
    }                                                                             \
    __syncthreads();                                                              \
  }                                                                               \
  int cq = (lane >> 4) * 4;

// variant 1: dual fp16 output (cols < F -> Cl stride F; cols >= F -> Cr stride F)
__global__ __launch_bounds__(256) void gemm_f16_dual_k(const unsigned short* __restrict__ A,
                                                       const unsigned short* __restrict__ Bt,
                                                       _Float16* __restrict__ Cl,
                                                       _Float16* __restrict__ Cr,
                                                       int M, int Ncols, int K, int lda) {
  MFMA_CORE64(A, Bt, lda, K)
#pragma unroll
  for (int i = 0; i < 4; ++i) {
#pragma unroll
    for (int j = 0; j < 4; ++j) {
      int col = n0 + wc + 16 * j + fr;
      if (col >= Ncols) continue;
      int rowb = m0 + wr + 16 * i + cq;
#pragma unroll
      for (int r = 0; r < 4; ++r) {
        int row = rowb + r;
        if (row >= M) continue;
        float v = acc[i][j][r];
        if (col < F) Cl[(size_t)row * F + col] = (_Float16)v;
        else         Cr[(size_t)row * F + (col - F)] = (_Float16)v;
      }
    }
  }
}

// variant 2: fp16 output, row stride Ncols (feeds the packed-fp16 GCN aggregation)
__global__ __launch_bounds__(256) void gemm_f16o_k(const unsigned short* __restrict__ A,
                                                   const unsigned short* __restrict__ Bt,
                                                   _Float16* __restrict__ C,
                                                   int M, int Ncols, int K, int lda) {
  MFMA_CORE64(A, Bt, lda, K)
#pragma unroll
  for (int i = 0; i < 4; ++i) {
#pragma unroll
    for (int j = 0; j < 4; ++j) {
      int col = n0 + wc + 16 * j + fr;
      if (col >= Ncols) continue;
      int rowb = m0 + wr + 16 * i + cq;
#pragma unroll
      for (int r = 0; r < 4; ++r) {
        int row = rowb + r;
        if (row < M) C[(size_t)row * Ncols + col] = (_Float16)acc[i][j][r];
      }
    }
  }
}

// variant 3 (FC1): bias+relu epilogue, bf16 output stride N2PAD, zero pad cols >= Nreal
__global__ __launch_bounds__(256) void gemm_bf16_fc1_k(const unsigned short* __restrict__ A,
                                                       const unsigned short* __restrict__ Bt,
                                                       const float* __restrict__ bias,
                                                       __hip_bfloat16* __restrict__ C,
                                                       int M, int Nreal, int K, int lda) {
  MFMA_CORE64(A, Bt, lda, K)
#pragma unroll
  for (int i = 0; i < 4; ++i) {
#pragma unroll
    for (int j = 0; j < 4; ++j) {
      int col = n0 + wc + 16 * j + fr;
      int rowb = m0 + wr + 16 * i + cq;
#pragma unroll
      for (int r = 0; r < 4; ++r) {
        int row = rowb + r;
        if (row >= M) continue;
        float v = 0.f;
        if (col < Nreal) v = fmaxf(acc[i][j][r] + bias[col], 0.f);
        C[(size_t)row * N2PAD + col] = __float2bfloat16(v);
      }
    }
  }
}

// variant 4 (FC2): split-K over blockIdx.z, f32 atomicAdd into pre-initialized C [M x 128]
__global__ __launch_bounds__(256) void gemm_bf16_fc2_k(const unsigned short* __restrict__ A,
                                                       const unsigned short* __restrict__ Bt,
                                                       float* C, int M, int kchunk) {
  const unsigned short* A2 = A + (size_t)blockIdx.z * kchunk;
  const unsigned short* B2 = Bt + (size_t)blockIdx.z * kchunk;
  MFMA_CORE64(A2, B2, N2PAD, kchunk)
#pragma unroll
  for (int i = 0; i < 4; ++i) {
#pragma unroll
    for (int j = 0; j < 4; ++j) {
      int col = n0 + wc + 16 * j + fr;   // n0 == 0, col < 128
      int rowb = m0 + wr + 16 * i + cq;
#pragma unroll
      for (int r = 0; r < 4; ++r) {
        int row = rowb + r;
        if (row < M && col < 128) atomicAdd(&C[(size_t)row * 128 + col], acc[i][j][r]);
      }
    }
  }
}

// ---------------- CSR build (by dst, self-loop first per node) ----------------
// merged scan + node_init: counts[] holds EDGE counts (no self-loop); degree = c+1.
// Per element: row_start, self-loop slot, cursor, dinv — all from in-register run.
__global__ __launch_bounds__(1024) void scan_k(const int* __restrict__ counts,
                                               int* __restrict__ row_start,
                                               int* __restrict__ csr_src,
                                               int* __restrict__ cursor,
                                               float* __restrict__ dinv, int Nn) {
  __shared__ int part[1024];
  int t = threadIdx.x;
  int chunk = (Nn + 1023) / 1024;
  int b0 = t * chunk, b1 = min(b0 + chunk, Nn);
  int s = 0;
  for (int i = b0; i < b1; ++i) s += counts[i] + 1;
  part[t] = s;
  __syncthreads();
  // Hillis-Steele inclusive scan over 1024 partials
  for (int off = 1; off < 1024; off <<= 1) {
    int u = (t >= off) ? part[t - off] : 0;
    __syncthreads();
    part[t] += u;
    __syncthreads();
  }
  int run = part[t] - s;   // exclusive prefix for this thread's chunk
  for (int i = b0; i < b1; ++i) {
    int c = counts[i] + 1;             // degree incl. self-loop
    row_start[i] = run;
    csr_src[run] = i;                  // self-loop first
    cursor[i] = run + 1;
    dinv[i] = rsqrtf((float)c);
    run += c;
  }
  if (t == 1023) row_start[Nn] = run;
}
__global__ void scatter_k(const int* __restrict__ srcv, const int* __restrict__ dstv, int E,
                          int* cursor, int* csr_src) {
  for (int e = blockIdx.x * blockDim.x + threadIdx.x; e < E; e += gridDim.x * blockDim.x) {
    int pos = atomicAdd(&cursor[dstv[e]], 1);
    csr_src[pos] = srcv[e];
  }
}

// ---------------- GATv2 fused, PACKED fp16, offset-staged 3-deep pipeline ----------
// (round-7 proven config: 3-deep data stages + 1-ahead offsets, 16 VGPR, ~100us)
// per-dst block, 320 thr = 10 heads x 32 lanes; 2 dword gathers/edge (high MLP).
// att pre-scaled by log2e -> raw 2^x. Reduce: 4 DPP adds + xor16 shuffle.
#define GAT_EDGE(U0, U1)                                                       \
  { h2 x0 = __builtin_bit_cast(h2, U0);                                        \
    h2 x1 = __builtin_bit_cast(h2, U1);                                        \
    h2 v0 = x0 + xr0;                                                          \
    h2 v1 = x1 + xr1;                                                          \
    h2 l0 = __builtin_elementwise_max(v0, v0 * ns2);                           \
    h2 l1 = __builtin_elementwise_max(v1, v1 * ns2);                           \
    float p = __builtin_amdgcn_fdot2(l1, at1,                                  \
                __builtin_amdgcn_fdot2(l0, at0, 0.f, false), false);           \
    p = DPP_ADDF(p, 0xB1);                                                     \
    p = DPP_ADDF(p, 0x4E);                                                     \
    p = DPP_ADDF(p, 0x141);                                                    \
    p = DPP_ADDF(p, 0x140);                                                    \
    p = xor16_sum(p);                                                          \
    p = EXP2F(p);                                                              \
    denom += p;                                                                \
    h2 ph = __builtin_amdgcn_cvt_pkrtz(p, p);                                  \
    acc0 += ph * x0;                                                           \
    acc1 += ph * x1; }

__global__ __launch_bounds__(320) void gatv2_fused_k(const _Float16* __restrict__ xl,
                                                     const _Float16* __restrict__ xr,
                                                     const float* __restrict__ att,
                                                     const float* __restrict__ b_gat,
                                                     const int* __restrict__ row_start,
                                                     const int* __restrict__ csr_src,
                                                     __hip_bfloat16* __restrict__ h1out) {
  int dst = blockIdx.x;
  int t = threadIdx.x;
  int h = t >> 5, w = t & 31;
  int hb = h * CH;
  bool hasP1 = (w < 7);
  int c0 = hb + 2 * w;
  int c1 = hb + 64 + 2 * w;
  const h2 ns2 = {(__fp16)NEG, (__fp16)NEG};
  const unsigned short* xru = (const unsigned short*)xr + (size_t)dst * F;
  h2 xr0 = __builtin_bit_cast(h2, *(const unsigned int*)(xru + c0));
  unsigned int uxr1 = hasP1 ? *(const unsigned int*)(xru + c1) : 0u;
  h2 xr1 = __builtin_bit_cast(h2, uxr1);
  // att pre-scaled by log2e (softmax invariant: 2^(log2e*z) == e^z)
  h2 at0 = __builtin_amdgcn_cvt_pkrtz(att[c0] * LOG2E, att[c0 + 1] * LOG2E);
  h2 at1 = hasP1 ? __builtin_amdgcn_cvt_pkrtz(att[c1] * LOG2E, att[c1 + 1] * LOG2E)
                 : __builtin_amdgcn_cvt_pkrtz(0.f, 0.f);
  int r0 = row_start[dst], r1 = row_start[dst + 1];
  float denom = 0.f;
  h2 acc0 = {(__fp16)0, (__fp16)0};
  h2 acc1 = {(__fp16)0, (__fp16)0};
  // hoisted gather bases: one lshl_add_u64 per gather in the loop
  const unsigned short* xl0 = (const unsigned short*)xl + c0;
  const unsigned short* xl1 = (const unsigned short*)xl + c1;

  // stages: data A,B = edges j,j+1 (processing); data C,D = j+2,j+3;
  // row offsets oE,oF = j+4,j+5. All OOB prefetch clamps to r0 (never processed).
  unsigned int uA0, uA1, uB0, uB1, uC0, uC1, uD0, uD1;
  unsigned oE, oF;
  {
    int i1 = (r0 + 1 < r1) ? r0 + 1 : r0;
    int i2 = (r0 + 2 < r1) ? r0 + 2 : r0;
    int i3 = (r0 + 3 < r1) ? r0 + 3 : r0;
    int i4 = (r0 + 4 < r1) ? r0 + 4 : r0;
    int i5 = (r0 + 5 < r1) ? r0 + 5 : r0;
    unsigned oA = (unsigned)csr_src[r0] * 780u;
    unsigned oB = (unsigned)csr_src[i1] * 780u;
    unsigned oC = (unsigned)csr_src[i2] * 780u;
    unsigned oD = (unsigned)csr_src[i3] * 780u;
    oE = (unsigned)csr_src[i4] * 780u;
    oF = (unsigned)csr_src[i5] * 780u;
    uA0 = *(const unsigned int*)(xl0 + oA);
    uA1 = hasP1 ? *(const unsigned int*)(xl1 + oA) : 0u;
    uB0 = *(const unsigned int*)(xl0 + oB);
    uB1 = hasP1 ? *(const unsigned int*)(xl1 + oB) : 0u;
    uC0 = *(const unsigned int*)(xl0 + oC);
    uC1 = hasP1 ? *(const unsigned int*)(xl1 + oC) : 0u;
    uD0 = *(const unsigned int*)(xl0 + oD);
    uD1 = hasP1 ? *(const unsigned int*)(xl1 + oD) : 0u;
  }
  int j = r0;
#pragma unroll 2
  for (; j + 1 < r1; j += 2) {
    int i6 = j + 6; i6 = (i6 < r1) ? i6 : r0;
    int i7 = j + 7; i7 = (i7 < r1) ? i7 : r0;
    unsigned nE = (unsigned)csr_src[i6] * 780u;     // offsets for next iter
    unsigned nF = (unsigned)csr_src[i7] * 780u;
    unsigned int gE0 = *(const unsigned int*)(xl0 + oE);   // data j+4,j+5
    unsigned int gE1 = hasP1 ? *(const unsigned int*)(xl1 + oE) : 0u;
    unsigned int gF0 = *(const unsigned int*)(xl0 + oF);
    unsigned int gF1 = hasP1 ? *(const unsigned int*)(xl1 + oF) : 0u;
    GAT_EDGE(uA0, uA1);
    GAT_EDGE(uB0, uB1);
    uA0 = uC0; uA1 = uC1; uB0 = uD0; uB1 = uD1;
    uC0 = gE0; uC1 = gE1; uD0 = gF0; uD1 = gF1;
    oE = nE; oF = nF;
  }
  if ((r1 - r0) & 1) GAT_EDGE(uA0, uA1);

  float inv = 1.f / denom;
  __hip_bfloat16* orow = h1out + (size_t)dst * KPAD;
  orow[c0] = __float2bfloat16(fmaxf((float)acc0.x * inv + b_gat[c0], 0.f));
  orow[c0 + 1] = __float2bfloat16(fmaxf((float)acc0.y * inv + b_gat[c0 + 1], 0.f));
  if (hasP1) {
    orow[c1] = __float2bfloat16(fmaxf((float)acc1.x * inv + b_gat[c1], 0.f));
    orow[c1 + 1] = __float2bfloat16(fmaxf((float)acc1.y * inv + b_gat[c1 + 1], 0.f));
  }
  if (t < KPAD - F) orow[F + t] = __float2bfloat16(0.f);
}

// ---------------- GCN aggregation, quad-per-lane (780 = 195 quads), 256 thr ----------
// Lane t < 195 covers channels 4t..4t+3: one uint2 gather + 2 pk_fma per edge.
// di factored out of per-edge norm (applied in epilogue). 4-deep pipeline:
// data A..F = edges j..j+5, indices sG,sH = j+6,j+7.
#define AGG_EDGE(U, NV)                                                        \
  { h2 nh = __builtin_amdgcn_cvt_pkrtz((NV), (NV));                            \
    a0 += nh * __builtin_bit_cast(h2, (U).x);                                  \
    a1 += nh * __builtin_bit_cast(h2, (U).y); }

__global__ __launch_bounds__(256) void gcn_agg_k(const _Float16* __restrict__ hmat,
                                                 const float* __restrict__ bias,
                                                 const int* __restrict__ row_start,
                                                 const int* __restrict__ csr_src,
                                                 const float* __restrict__ dinv,
                                                 __hip_bfloat16* __restrict__ out) {
  int dst = blockIdx.x;
  int t = threadIdx.x;
  int tq = (t < 195) ? t : 194;         // clamp: idle lanes duplicate last quad
  int q = 4 * tq;
  int r0 = row_start[dst], r1 = row_start[dst + 1];
  float di = dinv[dst];
  h2 a0 = {(__fp16)0, (__fp16)0};
  h2 a1 = {(__fp16)0, (__fp16)0};
  const unsigned short* hq = (const unsigned short*)hmat + q;   // hoisted base

#define AGG_LD(ss) (*(const uint2*)(hq + (size_t)(unsigned)(ss) * F))
  uint2 uA, uB, uC, uD, uE, uF;
  float nvA, nvB, nvC, nvD, nvE, nvF;
  int sG, sH;
  {
    int i1 = (r0 + 1 < r1) ? r0 + 1 : r0;
    int i2 = (r0 + 2 < r1) ? r0 + 2 : r0;
    int i3 = (r0 + 3 < r1) ? r0 + 3 : r0;
    int i4 = (r0 + 4 < r1) ? r0 + 4 : r0;
    int i5 = (r0 + 5 < r1) ? r0 + 5 : r0;
    int i6 = (r0 + 6 < r1) ? r0 + 6 : r0;
    int i7 = (r0 + 7 < r1) ? r0 + 7 : r0;
    int s0 = csr_src[r0], s1 = csr_src[i1], s2 = csr_src[i2], s3 = csr_src[i3];
    int s4 = csr_src[i4], s5 = csr_src[i5];
    sG = csr_src[i6]; sH = csr_src[i7];
    nvA = dinv[s0]; nvB = dinv[s1]; nvC = dinv[s2]; nvD = dinv[s3];
    nvE = dinv[s4]; nvF = dinv[s5];
    uA = AGG_LD(s0); uB = AGG_LD(s1); uC = AGG_LD(s2); uD = AGG_LD(s3);
    uE = AGG_LD(s4); uF = AGG_LD(s5);
  }
  int j = r0;
#pragma unroll 2
  for (; j + 1 < r1; j += 2) {
    int i8 = j + 8; i8 = (i8 < r1) ? i8 : r0;
    int i9 = j + 9; i9 = (i9 < r1) ? i9 : r0;
    int nsG = csr_src[i8];
    int nsH = csr_src[i9];
    uint2 gG = AGG_LD(sG);
    uint2 gH = AGG_LD(sH);
    float nG = dinv[sG];
    float nH = dinv[sH];
    AGG_EDGE(uA, nvA);
    AGG_EDGE(uB, nvB);
    uA = uC; nvA = nvC; uB = uD; nvB = nvD;
    uC = uE; nvC = nvE; uD = uF; nvD = nvF;
    uE = gG; nvE = nG; uF = gH; nvF = nH;
    sG = nsG; sH = nsH;
  }
  if ((r1 - r0) & 1) AGG_EDGE(uA, nvA);
#undef AGG_LD

  if (t < 195) {
    __hip_bfloat16* o = out + (size_t)dst * F + q;
    o[0] = __float2bfloat16(fmaxf(di * (float)a0.x + bias[q], 0.f));
    o[1] = __float2bfloat16(fmaxf(di * (float)a0.y + bias[q + 1], 0.f));
    o[2] = __float2bfloat16(fmaxf(di * (float)a1.x + bias[q + 2], 0.f));
    o[3] = __float2bfloat16(fmaxf(di * (float)a1.y + bias[q + 3], 0.f));
  }
}

// ---------------- pooling: bf16 in; per-graph max & mean; bf16 pooled [NGRAPH x K2PAD] ----
__global__ __launch_bounds__(320) void pool_k(const __hip_bfloat16* __restrict__ hmat,
                                              const int* __restrict__ batch,
                                              __hip_bfloat16* __restrict__ pooled, int Nn) {
  int g = blockIdx.x;
  int t = threadIdx.x;
  __shared__ int lo_s, hi_s;
  if (t == 0) {
    int lo = 0, hi = Nn;
    while (lo < hi) { int mid = (lo + hi) >> 1; if (batch[mid] < g) lo = mid + 1; else hi = mid; }
    lo_s = lo;
    int lo2 = lo, hi2 = Nn;
    while (lo2 < hi2) { int mid = (lo2 + hi2) >> 1; if (batch[mid] < g + 1) lo2 = mid + 1; else hi2 = mid; }
    hi_s = lo2;
  }
  __syncthreads();
  int lo = lo_s, hi = hi_s, cnt = hi - lo;
  bool hasP1 = (t < 70);
  int c0 = 2 * t;
  int c1 = 640 + 2 * t;
  float m0a = -1e30f, m0b = -1e30f, m1a = -1e30f, m1b = -1e30f;
  float s0a = 0.f, s0b = 0.f, s1a = 0.f, s1b = 0.f;
  const unsigned short* hu = (const unsigned short*)hmat;
  for (int n = lo; n < hi; ++n) {
    const unsigned short* hp = hu + (size_t)n * F;
    unsigned int u0 = *(const unsigned int*)(hp + c0);
    float v0x, v0y;
    bf2unpack(u0, v0x, v0y);
    m0a = fmaxf(m0a, v0x); s0a += v0x;
    m0b = fmaxf(m0b, v0y); s0b += v0y;
    if (hasP1) {
      unsigned int u1 = *(const unsigned int*)(hp + c1);
      float v1x, v1y;
      bf2unpack(u1, v1x, v1y);
      m1a = fmaxf(m1a, v1x); s1a += v1x;
      m1b = fmaxf(m1b, v1y); s1b += v1y;
    }
  }
  float inv = 1.f / (float)(cnt > 0 ? cnt : 1);
  __hip_bfloat16* o = pooled + (size_t)g * K2PAD;
  o[c0] = __float2bfloat16(cnt ? m0a : 0.f);
  o[c0 + 1] = __float2bfloat16(cnt ? m0b : 0.f);
  o[780 + c0] = __float2bfloat16(s0a * inv);
  o[780 + c0 + 1] = __float2bfloat16(s0b * inv);
  if (hasP1) {
    o[c1] = __float2bfloat16(cnt ? m1a : 0.f);
    o[c1 + 1] = __float2bfloat16(cnt ? m1b : 0.f);
    o[780 + c1] = __float2bfloat16(s1a * inv);
    o[780 + c1 + 1] = __float2bfloat16(s1b * inv);
  }
  if (t < K2PAD - 1560) o[1560 + t] = __float2bfloat16(0.f);
}

// ---------------- launcher ----------------
extern "C" void kernel_launch(void* const* d_in, const int* in_sizes, int n_in,
                              void* d_out, int out_size, void* d_ws, size_t ws_size,
                              hipStream_t stream) {
  const float* x     = (const float*)d_in[0];
  const int*   ei    = (const int*)d_in[1];
  const int*   batch = (const int*)d_in[2];
  const float* Wl    = (const float*)d_in[3];
  const float* Wr    = (const float*)d_in[4];
  const float* att   = (const float*)d_in[5];
  const float* b_gat = (const float*)d_in[6];
  const float* W_gcn = (const float*)d_in[7];
  const float* b_gcn = (const float*)d_in[8];
  const float* W_fc1 = (const float*)d_in[9];
  const float* b_fc1 = (const float*)d_in[10];
  const float* W_fc2 = (const float*)d_in[11];
  const float* b_fc2 = (const float*)d_in[12];
  float* out = (float*)d_out;

  int Nn = in_sizes[0] / 78;   // 16384
  int E  = in_sizes[1] / 2;    // 262144
  int EP = E + Nn;             // with self-loops
  const int* srcv = ei;
  const int* dstv = ei + E;

  // workspace layout
  char* wsb = (char*)d_ws;
  size_t NB = (size_t)Nn * F;
  _Float16* xrh = (_Float16*)wsb;                             // [Nn*F] fp16: xr; later aggbf
  __hip_bfloat16* aggbf = (__hip_bfloat16*)wsb;               // alias (xr dead by then)
  wsb += NB * sizeof(_Float16);
  _Float16* bufH = (_Float16*)wsb;                            // [Nn*F] fp16: xl, then h2
  wsb += NB * sizeof(_Float16);
  __hip_bfloat16* h1bf = (__hip_bfloat16*)wsb;                // [Nn*KPAD] bf16: GAT out
  wsb += (size_t)Nn * KPAD * sizeof(__hip_bfloat16);
  __hip_bfloat16* xbf = (__hip_bfloat16*)wsb;                 // [Nn*K1] bf16
  wsb += (size_t)Nn * K1 * sizeof(__hip_bfloat16);
  __hip_bfloat16* Wlrb = (__hip_bfloat16*)wsb;                // [N1PAD*K1]
  wsb += (size_t)N1PAD * K1 * sizeof(__hip_bfloat16);
  __hip_bfloat16* Wtb = (__hip_bfloat16*)wsb;                 // [NPAD*KPAD]
  wsb += (size_t)NPAD * KPAD * sizeof(__hip_bfloat16);
  __hip_bfloat16* Wfc1b = (__hip_bfloat16*)wsb;               // [N2PAD*K2PAD]
  wsb += (size_t)N2PAD * K2PAD * sizeof(__hip_bfloat16);
  __hip_bfloat16* Wfc2b = (__hip_bfloat16*)wsb;               // [128*N2PAD]
  wsb += (size_t)128 * N2PAD * sizeof(__hip_bfloat16);
  __hip_bfloat16* pooledb = (__hip_bfloat16*)wsb;             // [NGRAPH*K2PAD]
  wsb += (size_t)NGRAPH * K2PAD * sizeof(__hip_bfloat16);
  __hip_bfloat16* g1b = (__hip_bfloat16*)wsb;                 // [NGRAPH*N2PAD] FC1 out
  wsb += (size_t)NGRAPH * N2PAD * sizeof(__hip_bfloat16);
  int* csr_src = (int*)wsb;      wsb += (size_t)EP * sizeof(int);
  int* counts = (int*)wsb;       wsb += (size_t)Nn * sizeof(int);
  int* row_start = (int*)wsb;    wsb += (size_t)(Nn + 1) * sizeof(int);
  int* cursor = (int*)wsb;       wsb += (size_t)Nn * sizeof(int);
  float* dinv = (float*)wsb;     wsb += (size_t)Nn * sizeof(float);
  size_t need = (size_t)(wsb - (char*)d_ws);
  if (need > ws_size) {
    fprintf(stderr, "kernel_launch: ws too small: need %zu have %zu\n", need, ws_size);
  }

  dim3 blk(256);

  // zero edge counts (self-loop +1 applied in scan_k)
  hipMemsetAsync(counts, 0, (size_t)Nn * sizeof(int), stream);

  // merged preprocessing: all casts + out=bias + edge counting
  int prep_total = Nn * K1 + N1PAD * K1 + NPAD * KPAD + N2PAD * K2PAD + 128 * N2PAD
                 + NGRAPH * 128 + E;
  prep_k<<<(prep_total + 255) / 256, 256, 0, stream>>>(x, Wl, Wr, W_gcn, W_fc1, W_fc2, b_fc2,
                                                       dstv, xbf, Wlrb, Wtb, Wfc1b, Wfc2b,
                                                       out, counts, Nn, E);

  // CSR by dst (self-loop slot first): merged scan + node_init, then scatter
  scan_k<<<1, 1024, 0, stream>>>(counts, row_start, csr_src, cursor, dinv, Nn);
  scatter_k<<<512, 256, 0, stream>>>(srcv, dstv, E, cursor, csr_src);

  // transform GEMM (bf16 MFMA, BK=64): xbf @ Wlrb^T -> xl (bufH) | xr (xrh), both fp16
  dim3 g1grid(N1PAD / 128, Nn / 128);
  gemm_f16_dual_k<<<g1grid, blk, 0, stream>>>((const unsigned short*)xbf,
                                              (const unsigned short*)Wlrb,
                                              bufH, xrh, Nn, N1, K1, K1);

  // GATv2 fused single-pass (packed fp16) -> h1bf (bf16, KPAD stride, padded cols zeroed)
  gatv2_fused_k<<<Nn, 320, 0, stream>>>(bufH, xrh, att, b_gat, row_start, csr_src, h1bf);

  // GCN matmul (bf16 MFMA, BK=64): h1bf @ Wtb^T -> h2 fp16 (bufH, xl dead), stride F
  dim3 g2grid(NPAD / 128, Nn / 128);
  gemm_f16o_k<<<g2grid, blk, 0, stream>>>((const unsigned short*)h1bf,
                                          (const unsigned short*)Wtb,
                                          bufH, Nn, F, KPAD, KPAD);

  // normalized aggregation (quad-per-lane fp16 gather) -> bf16 aggbf (aliases dead xr)
  gcn_agg_k<<<Nn, 256, 0, stream>>>(bufH, b_gcn, row_start, csr_src, dinv, aggbf);

  // pooling (bf16 in) -> bf16 pooled [NGRAPH x K2PAD], zero-padded
  pool_k<<<NGRAPH, 320, 0, stream>>>(aggbf, batch, pooledb, Nn);

  // FC1 (bf16 MFMA, BK=64): g1b = relu(pooled @ Wfc1b^T + b_fc1), bf16, padded to N2PAD
  dim3 fc1grid(N2PAD / 128, NGRAPH / 128);
  gemm_bf16_fc1_k<<<fc1grid, blk, 0, stream>>>((const unsigned short*)pooledb,
                                               (const unsigned short*)Wfc1b,
                                               b_fc1, g1b, NGRAPH, 1500, K2PAD, K2PAD);

  // FC2 (bf16 MFMA split-K): out += g1b @ Wfc2b^T (out pre-inited with b_fc2)
  dim3 fc2grid(1, NGRAPH / 128, 6);   // kchunk 256 -> 4 BK iters per block
  gemm_bf16_fc2_k<<<fc2grid, blk, 0, stream>>>((const unsigned short*)g1b,
                                               (const unsigned short*)Wfc2b,
                                               out, NGRAPH, 256);
}

// Round 13
// 460.698 us; speedup vs baseline: 1.0501x; 1.0501x over previous
//
#include <hip/hip_runtime.h>
#include <hip/hip_bf16.h>
#include <math.h>
#include <stdio.h>

#define HEADS 10
#define CH 78
#define F 780          // HEADS*CH
#define NGRAPH 512
#define NEG 0.2f
#define LOG2E 1.44269504f
#define KPAD 832       // GCN GEMM K: 780 padded to mult of 64
#define NPAD 896       // GCN GEMM N: 780 padded to mult of 128
#define K1 128         // transform GEMM K: 78 padded to mult of 64
#define N1 1560        // transform GEMM N: 780 (xl) + 780 (xr)
#define N1PAD 1664     // 1560 padded to mult of 128
#define K2PAD 1600     // FC1 K: 1560 padded to mult of 64
#define N2PAD 1536     // FC1 N: 1500 padded to mult of 128 (also FC2 K with zero pad)

typedef __attribute__((ext_vector_type(8))) short short8;
typedef __attribute__((ext_vector_type(4))) float f32x4;
typedef __fp16 __attribute__((ext_vector_type(2))) h2;   // packed fp16 pair (VOP3P)

__device__ inline void bf2unpack(unsigned int u, float& lo, float& hi) {
  union { unsigned int ui; float f; } a, b;
  a.ui = u << 16;
  b.ui = u & 0xffff0000u;
  lo = a.f; hi = b.f;
}

// VALU-pipe cross-lane add via DPP (dep latency ~4-8cy vs ds_swizzle ~30cy).
#define DPP_ADDF(v, ctrl)                                                      \
  ((v) + __builtin_bit_cast(float, __builtin_amdgcn_update_dpp(                \
             0, __builtin_bit_cast(int, (v)), ctrl, 0xF, 0xF, true)))

// xor16 within each 32-lane group. NOTE: permlane16_swap(p,p) is UNSAFE here —
// same-value operands can be allocated to one physical register, making the HW
// swap self-referential (round-6 correctness regression). Keep the shuffle.
__device__ inline float xor16_sum(float p) { return p + __shfl_xor(p, 16, 32); }

// raw 2^x (att is pre-scaled by log2e, so no v_mul needed)
#if __has_builtin(__builtin_amdgcn_exp2f)
#define EXP2F(x) __builtin_amdgcn_exp2f(x)
#else
#define EXP2F(x) exp2f(x)
#endif

// ---------------- merged preprocessing: casts + counts init + out init ----------
__global__ __launch_bounds__(256) void prep_k(const float* __restrict__ x,
                                              const float* __restrict__ Wl,
                                              const float* __restrict__ Wr,
                                              const float* __restrict__ Wgcn,
                                              const float* __restrict__ Wfc1,
                                              const float* __restrict__ Wfc2,
                                              const float* __restrict__ bfc2,
                                              __hip_bfloat16* __restrict__ xb,
                                              __hip_bfloat16* __restrict__ Wlrb,
                                              __hip_bfloat16* __restrict__ Wtb,
                                              __hip_bfloat16* __restrict__ Wfc1b,
                                              __hip_bfloat16* __restrict__ Wfc2b,
                                              float* __restrict__ outinit,
                                              int* __restrict__ counts, int Nn) {
  int i = blockIdx.x * 256 + threadIdx.x;
  int s0 = Nn * K1;
  int s1 = s0 + N1PAD * K1;
  int s2 = s1 + NPAD * KPAD;
  int s3 = s2 + N2PAD * K2PAD;
  int s4 = s3 + 128 * N2PAD;
  int s5 = s4 + NGRAPH * 128;
  int s6 = s5 + Nn;
  if (i < s0) {
    int row = i / K1, k = i - row * K1;
    xb[i] = __float2bfloat16((k < 78) ? x[(size_t)row * 78 + k] : 0.f);
  } else if (i < s1) {
    int j = i - s0;
    int n = j / K1, k = j - n * K1;
    float v = 0.f;
    if (k < 78 && n < N1) v = (n < F) ? Wl[(size_t)k * F + n] : Wr[(size_t)k * F + (n - F)];
    Wlrb[j] = __float2bfloat16(v);
  } else if (i < s2) {
    int j = i - s1;
    int n = j / KPAD, k = j - n * KPAD;
    float v = (n < F && k < F) ? Wgcn[(size_t)k * F + n] : 0.f;
    Wtb[j] = __float2bfloat16(v);
  } else if (i < s3) {
    int j = i - s2;
    int n = j / K2PAD, k = j - n * K2PAD;
    float v = (n < 1500 && k < 1560) ? Wfc1[(size_t)k * 1500 + n] : 0.f;
    Wfc1b[j] = __float2bfloat16(v);
  } else if (i < s4) {
    int j = i - s3;
    int n = j / N2PAD, k = j - n * N2PAD;     // n: out col 0..127, k: 0..1535
    float v = (k < 1500) ? Wfc2[(size_t)k * 128 + n] : 0.f;
    Wfc2b[j] = __float2bfloat16(v);
  } else if (i < s5) {
    int j = i - s4;
    outinit[j] = bfc2[j & 127];
  } else if (i < s6) {
    counts[i - s5] = 1;   // self-loop
  }
}

// ---------------- bf16 MFMA GEMM core, BK=64 ----------------
__device__ inline void gl_lds16(const unsigned short* g, unsigned short* l) {
  __builtin_amdgcn_global_load_lds(
      (const __attribute__((address_space(1))) unsigned int*)g,
      (__attribute__((address_space(3))) unsigned int*)l, 16, 0, 0);
}

// A: [M][lda] bf16 row-major, Bt: [Ncols_pad][lda] bf16 (B transposed). K mult of 64.
// 128x128 tile, 4 waves x (4x4) mfma_f32_16x16x32_bf16.
// XCD-aware block swizzle (applied when gridDim.y % 8 == 0): all x-blocks that
// share one 128-row A-panel land on the SAME XCD (wg->XCD round-robins linear id),
// so the panel is fetched from HBM once per panel instead of once per x-block.
// Bijective: by = (lid&7) + 8*((lid>>3)/gx); bx = (lid>>3)%gx.
#define MFMA_CORE64(A, Bt, lda, K)                                                \
  __shared__ unsigned short As[128 * 64];                                         \
  __shared__ unsigned short Bs[128 * 64];                                         \
  int tid = threadIdx.x;                                                          \
  int wave = tid >> 6, lane = tid & 63;                                           \
  int bx_ = blockIdx.x, by_ = blockIdx.y;                                         \
  { int gx = gridDim.x, gy = gridDim.y;                                           \
    if ((gy & 7) == 0) {                                                          \
      int lid = by_ * gx + bx_;                                                   \
      int c = lid & 7, s = lid >> 3;                                              \
      int yg = s / gx;                                                            \
      by_ = c + 8 * yg;                                                           \
      bx_ = s - yg * gx;                                                          \
    } }                                                                           \
  int m0 = by_ * 128, n0 = bx_ * 128;                                             \
  int wr = (wave >> 1) * 64, wc = (wave & 1) * 64;                                \
  f32x4 acc[4][4];                                                                \
  _Pragma("unroll")                                                               \
  for (int i = 0; i < 4; ++i)                                                     \
    _Pragma("unroll")                                                             \
    for (int j = 0; j < 4; ++j) acc[i][j] = (f32x4){0.f, 0.f, 0.f, 0.f};          \
  int lrow = lane >> 3;                                                           \
  int lcol = (lane & 7) * 8;                                                      \
  const unsigned short* gA0 = A + (size_t)(m0 + wave * 32 + lrow) * lda + lcol;   \
  const unsigned short* gB0 = Bt + (size_t)(n0 + wave * 32 + lrow) * lda + lcol;  \
  unsigned short* lA = As + (wave * 32) * 64;                                     \
  unsigned short* lB = Bs + (wave * 32) * 64;                                     \
  int q8 = (lane >> 4) * 8;                                                       \
  int fr = lane & 15;                                                             \
  for (int k0 = 0; k0 < K; k0 += 64) {                                            \
    _Pragma("unroll")                                                             \
    for (int c = 0; c < 4; ++c) {                                                 \
      gl_lds16(gA0 + (size_t)(8 * c) * lda, lA + (8 * c) * 64);                   \
      gl_lds16(gB0 + (size_t)(8 * c) * lda, lB + (8 * c) * 64);                   \
    }                                                                             \
    gA0 += 64; gB0 += 64;                                                         \
    __syncthreads();                                                              \
    _Pragma("unroll")                                                             \
    for (int ks = 0; ks < 64; ks += 32) {                                         \
      short8 a[4], b[4];                                                          \
      _Pragma("unroll")                                                           \
      for (int i = 0; i < 4; ++i) a[i] = *(const short8*)&As[(wr + 16 * i + fr) * 64 + ks + q8]; \
      _Pragma("unroll")                                                           \
      for (int j = 0; j < 4; ++j) b[j] = *(const short8*)&Bs[(wc + 16 * j + fr) * 64 + ks + q8]; \
      _Pragma("unroll")                                                           \
      for (int i = 0; i < 4; ++i)                                                 \
        _Pragma("unroll")                                                         \
        for (int j = 0; j < 4; ++j)                                               \
          acc[i][j] = __builtin_amdgcn_mfma_f32_16x16x32_bf16(a[i], b[j], acc[i][j], 0, 0, 0); \
    }                                                                             \
    __syncthreads();                                                              \
  }                                                                               \
  int cq = (lane >> 4) * 4;

// variant 1: dual fp16 output (cols < F -> Cl stride F; cols >= F -> Cr stride F)
__global__ __launch_bounds__(256) void gemm_f16_dual_k(const unsigned short* __restrict__ A,
                                                       const unsigned short* __restrict__ Bt,
                                                       _Float16* __restrict__ Cl,
                                                       _Float16* __restrict__ Cr,
                                                       int M, int Ncols, int K, int lda) {
  MFMA_CORE64(A, Bt, lda, K)
#pragma unroll
  for (int i = 0; i < 4; ++i) {
#pragma unroll
    for (int j = 0; j < 4; ++j) {
      int col = n0 + wc + 16 * j + fr;
      if (col >= Ncols) continue;
      int rowb = m0 + wr + 16 * i + cq;
#pragma unroll
      for (int r = 0; r < 4; ++r) {
        int row = rowb + r;
        if (row >= M) continue;
        float v = acc[i][j][r];
        if (col < F) Cl[(size_t)row * F + col] = (_Float16)v;
        else         Cr[(size_t)row * F + (col - F)] = (_Float16)v;
      }
    }
  }
}

// variant 2: fp16 output, row stride Ncols (feeds the packed-fp16 GCN aggregation)
__global__ __launch_bounds__(256) void gemm_f16o_k(const unsigned short* __restrict__ A,
                                                   const unsigned short* __restrict__ Bt,
                                                   _Float16* __restrict__ C,
                                                   int M, int Ncols, int K, int lda) {
  MFMA_CORE64(A, Bt, lda, K)
#pragma unroll
  for (int i = 0; i < 4; ++i) {
#pragma unroll
    for (int j = 0; j < 4; ++j) {
      int col = n0 + wc + 16 * j + fr;
      if (col >= Ncols) continue;
      int rowb = m0 + wr + 16 * i + cq;
#pragma unroll
      for (int r = 0; r < 4; ++r) {
        int row = rowb + r;
        if (row < M) C[(size_t)row * Ncols + col] = (_Float16)acc[i][j][r];
      }
    }
  }
}

// variant 3 (FC1): bias+relu epilogue, bf16 output stride N2PAD, zero pad cols >= Nreal
__global__ __launch_bounds__(256) void gemm_bf16_fc1_k(const unsigned short* __restrict__ A,
                                                       const unsigned short* __restrict__ Bt,
                                                       const float* __restrict__ bias,
                                                       __hip_bfloat16* __restrict__ C,
                                                       int M, int Nreal, int K, int lda) {
  MFMA_CORE64(A, Bt, lda, K)
#pragma unroll
  for (int i = 0; i < 4; ++i) {
#pragma unroll
    for (int j = 0; j < 4; ++j) {
      int col = n0 + wc + 16 * j + fr;
      int rowb = m0 + wr + 16 * i + cq;
#pragma unroll
      for (int r = 0; r < 4; ++r) {
        int row = rowb + r;
        if (row >= M) continue;
        float v = 0.f;
        if (col < Nreal) v = fmaxf(acc[i][j][r] + bias[col], 0.f);
        C[(size_t)row * N2PAD + col] = __float2bfloat16(v);
      }
    }
  }
}

// variant 4 (FC2): split-K over blockIdx.z, f32 atomicAdd into pre-initialized C [M x 128]
__global__ __launch_bounds__(256) void gemm_bf16_fc2_k(const unsigned short* __restrict__ A,
                                                       const unsigned short* __restrict__ Bt,
                                                       float* C, int M, int kchunk) {
  const unsigned short* A2 = A + (size_t)blockIdx.z * kchunk;
  const unsigned short* B2 = Bt + (size_t)blockIdx.z * kchunk;
  MFMA_CORE64(A2, B2, N2PAD, kchunk)
#pragma unroll
  for (int i = 0; i < 4; ++i) {
#pragma unroll
    for (int j = 0; j < 4; ++j) {
      int col = n0 + wc + 16 * j + fr;   // n0 == 0, col < 128
      int rowb = m0 + wr + 16 * i + cq;
#pragma unroll
      for (int r = 0; r < 4; ++r) {
        int row = rowb + r;
        if (row < M && col < 128) atomicAdd(&C[(size_t)row * 128 + col], acc[i][j][r]);
      }
    }
  }
}

// ---------------- CSR build (by dst, self-loop first per node) ----------------
__global__ void count_k(const int* __restrict__ dstv, int E, int* counts) {
  for (int e = blockIdx.x * blockDim.x + threadIdx.x; e < E; e += gridDim.x * blockDim.x)
    atomicAdd(&counts[dstv[e]], 1);
}
// widened: 1024 threads, chunk 16 (was 256/64 -> serial loads dominated)
__global__ __launch_bounds__(1024) void scan_k(const int* __restrict__ counts,
                                               int* __restrict__ row_start, int Nn) {
  __shared__ int part[1024];
  int t = threadIdx.x;
  int chunk = (Nn + 1023) / 1024;
  int b0 = t * chunk, b1 = min(b0 + chunk, Nn);
  int s = 0;
  for (int i = b0; i < b1; ++i) s += counts[i];
  part[t] = s;
  __syncthreads();
  // Hillis-Steele inclusive scan over 1024 partials
  for (int off = 1; off < 1024; off <<= 1) {
    int u = (t >= off) ? part[t - off] : 0;
    __syncthreads();
    part[t] += u;
    __syncthreads();
  }
  int run = part[t] - s;   // exclusive prefix for this thread's chunk
  for (int i = b0; i < b1; ++i) { row_start[i] = run; run += counts[i]; }
  if (t == 1023) row_start[Nn] = run;
}
// merged: self-loop slot + cursor init + dinv (parallel across 64 blocks)
__global__ void node_init_k(const int* __restrict__ row_start, int* cursor, int* csr_src,
                            float* dinv, int Nn) {
  int i = blockIdx.x * blockDim.x + threadIdx.x;
  if (i < Nn) {
    int p = row_start[i];
    csr_src[p] = i;
    cursor[i] = p + 1;
    dinv[i] = rsqrtf((float)(row_start[i + 1] - p));
  }
}
__global__ void scatter_k(const int* __restrict__ srcv, const int* __restrict__ dstv, int E,
                          int* cursor, int* csr_src) {
  for (int e = blockIdx.x * blockDim.x + threadIdx.x; e < E; e += gridDim.x * blockDim.x) {
    int pos = atomicAdd(&cursor[dstv[e]], 1);
    csr_src[pos] = srcv[e];
  }
}

// ---------------- GATv2 fused, PACKED fp16, offset-staged 3-deep pipeline ----------
// (round-7 proven config: 3-deep data stages + 1-ahead offsets, 16 VGPR, ~100us)
// per-dst block, 320 thr = 10 heads x 32 lanes; 2 dword gathers/edge (high MLP).
// att pre-scaled by log2e -> raw 2^x. Reduce: 4 DPP adds + xor16 shuffle.
#define GAT_EDGE(U0, U1)                                                       \
  { h2 x0 = __builtin_bit_cast(h2, U0);                                        \
    h2 x1 = __builtin_bit_cast(h2, U1);                                        \
    h2 v0 = x0 + xr0;                                                          \
    h2 v1 = x1 + xr1;                                                          \
    h2 l0 = __builtin_elementwise_max(v0, v0 * ns2);                           \
    h2 l1 = __builtin_elementwise_max(v1, v1 * ns2);                           \
    float p = __builtin_amdgcn_fdot2(l1, at1,                                  \
                __builtin_amdgcn_fdot2(l0, at0, 0.f, false), false);           \
    p = DPP_ADDF(p, 0xB1);                                                     \
    p = DPP_ADDF(p, 0x4E);                                                     \
    p = DPP_ADDF(p, 0x141);                                                    \
    p = DPP_ADDF(p, 0x140);                                                    \
    p = xor16_sum(p);                                                          \
    p = EXP2F(p);                                                              \
    denom += p;                                                                \
    h2 ph = __builtin_amdgcn_cvt_pkrtz(p, p);                                  \
    acc0 += ph * x0;                                                           \
    acc1 += ph * x1; }

__global__ __launch_bounds__(320) void gatv2_fused_k(const _Float16* __restrict__ xl,
                                                     const _Float16* __restrict__ xr,
                                                     const float* __restrict__ att,
                                                     const float* __restrict__ b_gat,
                                                     const int* __restrict__ row_start,
                                                     const int* __restrict__ csr_src,
                                                     __hip_bfloat16* __restrict__ h1out) {
  int dst = blockIdx.x;
  int t = threadIdx.x;
  int h = t >> 5, w = t & 31;
  int hb = h * CH;
  bool hasP1 = (w < 7);
  int c0 = hb + 2 * w;
  int c1 = hb + 64 + 2 * w;
  const h2 ns2 = {(__fp16)NEG, (__fp16)NEG};
  const unsigned short* xru = (const unsigned short*)xr + (size_t)dst * F;
  h2 xr0 = __builtin_bit_cast(h2, *(const unsigned int*)(xru + c0));
  unsigned int uxr1 = hasP1 ? *(const unsigned int*)(xru + c1) : 0u;
  h2 xr1 = __builtin_bit_cast(h2, uxr1);
  // att pre-scaled by log2e (softmax invariant: 2^(log2e*z) == e^z)
  h2 at0 = __builtin_amdgcn_cvt_pkrtz(att[c0] * LOG2E, att[c0 + 1] * LOG2E);
  h2 at1 = hasP1 ? __builtin_amdgcn_cvt_pkrtz(att[c1] * LOG2E, att[c1 + 1] * LOG2E)
                 : __builtin_amdgcn_cvt_pkrtz(0.f, 0.f);
  int r0 = row_start[dst], r1 = row_start[dst + 1];
  float denom = 0.f;
  h2 acc0 = {(__fp16)0, (__fp16)0};
  h2 acc1 = {(__fp16)0, (__fp16)0};
  // hoisted gather bases: one lshl_add_u64 per gather in the loop
  const unsigned short* xl0 = (const unsigned short*)xl + c0;
  const unsigned short* xl1 = (const unsigned short*)xl + c1;

  // stages: data A,B = edges j,j+1 (processing); data C,D = j+2,j+3;
  // row offsets oE,oF = j+4,j+5. All OOB prefetch clamps to r0 (never processed).
  unsigned int uA0, uA1, uB0, uB1, uC0, uC1, uD0, uD1;
  unsigned oE, oF;
  {
    int i1 = (r0 + 1 < r1) ? r0 + 1 : r0;
    int i2 = (r0 + 2 < r1) ? r0 + 2 : r0;
    int i3 = (r0 + 3 < r1) ? r0 + 3 : r0;
    int i4 = (r0 + 4 < r1) ? r0 + 4 : r0;
    int i5 = (r0 + 5 < r1) ? r0 + 5 : r0;
    unsigned oA = (unsigned)csr_src[r0] * 780u;
    unsigned oB = (unsigned)csr_src[i1] * 780u;
    unsigned oC = (unsigned)csr_src[i2] * 780u;
    unsigned oD = (unsigned)csr_src[i3] * 780u;
    oE = (unsigned)csr_src[i4] * 780u;
    oF = (unsigned)csr_src[i5] * 780u;
    uA0 = *(const unsigned int*)(xl0 + oA);
    uA1 = hasP1 ? *(const unsigned int*)(xl1 + oA) : 0u;
    uB0 = *(const unsigned int*)(xl0 + oB);
    uB1 = hasP1 ? *(const unsigned int*)(xl1 + oB) : 0u;
    uC0 = *(const unsigned int*)(xl0 + oC);
    uC1 = hasP1 ? *(const unsigned int*)(xl1 + oC) : 0u;
    uD0 = *(const unsigned int*)(xl0 + oD);
    uD1 = hasP1 ? *(const unsigned int*)(xl1 + oD) : 0u;
  }
  int j = r0;
#pragma unroll 2
  for (; j + 1 < r1; j += 2) {
    int i6 = j + 6; i6 = (i6 < r1) ? i6 : r0;
    int i7 = j + 7; i7 = (i7 < r1) ? i7 : r0;
    unsigned nE = (unsigned)csr_src[i6] * 780u;     // offsets for next iter
    unsigned nF = (unsigned)csr_src[i7] * 780u;
    unsigned int gE0 = *(const unsigned int*)(xl0 + oE);   // data j+4,j+5
    unsigned int gE1 = hasP1 ? *(const unsigned int*)(xl1 + oE) : 0u;
    unsigned int gF0 = *(const unsigned int*)(xl0 + oF);
    unsigned int gF1 = hasP1 ? *(const unsigned int*)(xl1 + oF) : 0u;
    GAT_EDGE(uA0, uA1);
    GAT_EDGE(uB0, uB1);
    uA0 = uC0; uA1 = uC1; uB0 = uD0; uB1 = uD1;
    uC0 = gE0; uC1 = gE1; uD0 = gF0; uD1 = gF1;
    oE = nE; oF = nF;
  }
  if ((r1 - r0) & 1) GAT_EDGE(uA0, uA1);

  float inv = 1.f / denom;
  __hip_bfloat16* orow = h1out + (size_t)dst * KPAD;
  orow[c0] = __float2bfloat16(fmaxf((float)acc0.x * inv + b_gat[c0], 0.f));
  orow[c0 + 1] = __float2bfloat16(fmaxf((float)acc0.y * inv + b_gat[c0 + 1], 0.f));
  if (hasP1) {
    orow[c1] = __float2bfloat16(fmaxf((float)acc1.x * inv + b_gat[c1], 0.f));
    orow[c1 + 1] = __float2bfloat16(fmaxf((float)acc1.y * inv + b_gat[c1 + 1], 0.f));
  }
  if (t < KPAD - F) orow[F + t] = __float2bfloat16(0.f);
}

// ---------------- GCN aggregation, quad-per-lane (780 = 195 quads), 256 thr ----------
// Lane t < 195 covers channels 4t..4t+3: one uint2 gather + 2 pk_fma per edge.
// di factored out of per-edge norm (applied in epilogue). 4-deep pipeline:
// data A..F = edges j..j+5, indices sG,sH = j+6,j+7.
#define AGG_EDGE(U, NV)                                                        \
  { h2 nh = __builtin_amdgcn_cvt_pkrtz((NV), (NV));                            \
    a0 += nh * __builtin_bit_cast(h2, (U).x);                                  \
    a1 += nh * __builtin_bit_cast(h2, (U).y); }

__global__ __launch_bounds__(256) void gcn_agg_k(const _Float16* __restrict__ hmat,
                                                 const float* __restrict__ bias,
                                                 const int* __restrict__ row_start,
                                                 const int* __restrict__ csr_src,
                                                 const float* __restrict__ dinv,
                                                 __hip_bfloat16* __restrict__ out) {
  int dst = blockIdx.x;
  int t = threadIdx.x;
  int tq = (t < 195) ? t : 194;         // clamp: idle lanes duplicate last quad
  int q = 4 * tq;
  int r0 = row_start[dst], r1 = row_start[dst + 1];
  float di = dinv[dst];
  h2 a0 = {(__fp16)0, (__fp16)0};
  h2 a1 = {(__fp16)0, (__fp16)0};
  const unsigned short* hq = (const unsigned short*)hmat + q;   // hoisted base

#define AGG_LD(ss) (*(const uint2*)(hq + (size_t)(unsigned)(ss) * F))
  uint2 uA, uB, uC, uD, uE, uF;
  float nvA, nvB, nvC, nvD, nvE, nvF;
  int sG, sH;
  {
    int i1 = (r0 + 1 < r1) ? r0 + 1 : r0;
    int i2 = (r0 + 2 < r1) ? r0 + 2 : r0;
    int i3 = (r0 + 3 < r1) ? r0 + 3 : r0;
    int i4 = (r0 + 4 < r1) ? r0 + 4 : r0;
    int i5 = (r0 + 5 < r1) ? r0 + 5 : r0;
    int i6 = (r0 + 6 < r1) ? r0 + 6 : r0;
    int i7 = (r0 + 7 < r1) ? r0 + 7 : r0;
    int s0 = csr_src[r0], s1 = csr_src[i1], s2 = csr_src[i2], s3 = csr_src[i3];
    int s4 = csr_src[i4], s5 = csr_src[i5];
    sG = csr_src[i6]; sH = csr_src[i7];
    nvA = dinv[s0]; nvB = dinv[s1]; nvC = dinv[s2]; nvD = dinv[s3];
    nvE = dinv[s4]; nvF = dinv[s5];
    uA = AGG_LD(s0); uB = AGG_LD(s1); uC = AGG_LD(s2); uD = AGG_LD(s3);
    uE = AGG_LD(s4); uF = AGG_LD(s5);
  }
  int j = r0;
#pragma unroll 2
  for (; j + 1 < r1; j += 2) {
    int i8 = j + 8; i8 = (i8 < r1) ? i8 : r0;
    int i9 = j + 9; i9 = (i9 < r1) ? i9 : r0;
    int nsG = csr_src[i8];
    int nsH = csr_src[i9];
    uint2 gG = AGG_LD(sG);
    uint2 gH = AGG_LD(sH);
    float nG = dinv[sG];
    float nH = dinv[sH];
    AGG_EDGE(uA, nvA);
    AGG_EDGE(uB, nvB);
    uA = uC; nvA = nvC; uB = uD; nvB = nvD;
    uC = uE; nvC = nvE; uD = uF; nvD = nvF;
    uE = gG; nvE = nG; uF = gH; nvF = nH;
    sG = nsG; sH = nsH;
  }
  if ((r1 - r0) & 1) AGG_EDGE(uA, nvA);
#undef AGG_LD

  if (t < 195) {
    __hip_bfloat16* o = out + (size_t)dst * F + q;
    o[0] = __float2bfloat16(fmaxf(di * (float)a0.x + bias[q], 0.f));
    o[1] = __float2bfloat16(fmaxf(di * (float)a0.y + bias[q + 1], 0.f));
    o[2] = __float2bfloat16(fmaxf(di * (float)a1.x + bias[q + 2], 0.f));
    o[3] = __float2bfloat16(fmaxf(di * (float)a1.y + bias[q + 3], 0.f));
  }
}

// ---------------- pooling: bf16 in; per-graph max & mean; bf16 pooled [NGRAPH x K2PAD] ----
__global__ __launch_bounds__(320) void pool_k(const __hip_bfloat16* __restrict__ hmat,
                                              const int* __restrict__ batch,
                                              __hip_bfloat16* __restrict__ pooled, int Nn) {
  int g = blockIdx.x;
  int t = threadIdx.x;
  __shared__ int lo_s, hi_s;
  if (t == 0) {
    int lo = 0, hi = Nn;
    while (lo < hi) { int mid = (lo + hi) >> 1; if (batch[mid] < g) lo = mid + 1; else hi = mid; }
    lo_s = lo;
    int lo2 = lo, hi2 = Nn;
    while (lo2 < hi2) { int mid = (lo2 + hi2) >> 1; if (batch[mid] < g + 1) lo2 = mid + 1; else hi2 = mid; }
    hi_s = lo2;
  }
  __syncthreads();
  int lo = lo_s, hi = hi_s, cnt = hi - lo;
  bool hasP1 = (t < 70);
  int c0 = 2 * t;
  int c1 = 640 + 2 * t;
  float m0a = -1e30f, m0b = -1e30f, m1a = -1e30f, m1b = -1e30f;
  float s0a = 0.f, s0b = 0.f, s1a = 0.f, s1b = 0.f;
  const unsigned short* hu = (const unsigned short*)hmat;
  for (int n = lo; n < hi; ++n) {
    const unsigned short* hp = hu + (size_t)n * F;
    unsigned int u0 = *(const unsigned int*)(hp + c0);
    float v0x, v0y;
    bf2unpack(u0, v0x, v0y);
    m0a = fmaxf(m0a, v0x); s0a += v0x;
    m0b = fmaxf(m0b, v0y); s0b += v0y;
    if (hasP1) {
      unsigned int u1 = *(const unsigned int*)(hp + c1);
      float v1x, v1y;
      bf2unpack(u1, v1x, v1y);
      m1a = fmaxf(m1a, v1x); s1a += v1x;
      m1b = fmaxf(m1b, v1y); s1b += v1y;
    }
  }
  float inv = 1.f / (float)(cnt > 0 ? cnt : 1);
  __hip_bfloat16* o = pooled + (size_t)g * K2PAD;
  o[c0] = __float2bfloat16(cnt ? m0a : 0.f);
  o[c0 + 1] = __float2bfloat16(cnt ? m0b : 0.f);
  o[780 + c0] = __float2bfloat16(s0a * inv);
  o[780 + c0 + 1] = __float2bfloat16(s0b * inv);
  if (hasP1) {
    o[c1] = __float2bfloat16(cnt ? m1a : 0.f);
    o[c1 + 1] = __float2bfloat16(cnt ? m1b : 0.f);
    o[780 + c1] = __float2bfloat16(s1a * inv);
    o[780 + c1 + 1] = __float2bfloat16(s1b * inv);
  }
  if (t < K2PAD - 1560) o[1560 + t] = __float2bfloat16(0.f);
}

// ---------------- launcher ----------------
extern "C" void kernel_launch(void* const* d_in, const int* in_sizes, int n_in,
                              void* d_out, int out_size, void* d_ws, size_t ws_size,
                              hipStream_t stream) {
  const float* x     = (const float*)d_in[0];
  const int*   ei    = (const int*)d_in[1];
  const int*   batch = (const int*)d_in[2];
  const float* Wl    = (const float*)d_in[3];
  const float* Wr    = (const float*)d_in[4];
  const float* att   = (const float*)d_in[5];
  const float* b_gat = (const float*)d_in[6];
  const float* W_gcn = (const float*)d_in[7];
  const float* b_gcn = (const float*)d_in[8];
  const float* W_fc1 = (const float*)d_in[9];
  const float* b_fc1 = (const float*)d_in[10];
  const float* W_fc2 = (const float*)d_in[11];
  const float* b_fc2 = (const float*)d_in[12];
  float* out = (float*)d_out;

  int Nn = in_sizes[0] / 78;   // 16384
  int E  = in_sizes[1] / 2;    // 262144
  int EP = E + Nn;             // with self-loops
  const int* srcv = ei;
  const int* dstv = ei + E;

  // workspace layout
  char* wsb = (char*)d_ws;
  size_t NB = (size_t)Nn * F;
  _Float16* xrh = (_Float16*)wsb;                             // [Nn*F] fp16: xr; later aggbf
  __hip_bfloat16* aggbf = (__hip_bfloat16*)wsb;               // alias (xr dead by then)
  wsb += NB * sizeof(_Float16);
  _Float16* bufH = (_Float16*)wsb;                            // [Nn*F] fp16: xl, then h2
  wsb += NB * sizeof(_Float16);
  __hip_bfloat16* h1bf = (__hip_bfloat16*)wsb;                // [Nn*KPAD] bf16: GAT out
  wsb += (size_t)Nn * KPAD * sizeof(__hip_bfloat16);
  __hip_bfloat16* xbf = (__hip_bfloat16*)wsb;                 // [Nn*K1] bf16
  wsb += (size_t)Nn * K1 * sizeof(__hip_bfloat16);
  __hip_bfloat16* Wlrb = (__hip_bfloat16*)wsb;                // [N1PAD*K1]
  wsb += (size_t)N1PAD * K1 * sizeof(__hip_bfloat16);
  __hip_bfloat16* Wtb = (__hip_bfloat16*)wsb;                 // [NPAD*KPAD]
  wsb += (size_t)NPAD * KPAD * sizeof(__hip_bfloat16);
  __hip_bfloat16* Wfc1b = (__hip_bfloat16*)wsb;               // [N2PAD*K2PAD]
  wsb += (size_t)N2PAD * K2PAD * sizeof(__hip_bfloat16);
  __hip_bfloat16* Wfc2b = (__hip_bfloat16*)wsb;               // [128*N2PAD]
  wsb += (size_t)128 * N2PAD * sizeof(__hip_bfloat16);
  __hip_bfloat16* pooledb = (__hip_bfloat16*)wsb;             // [NGRAPH*K2PAD]
  wsb += (size_t)NGRAPH * K2PAD * sizeof(__hip_bfloat16);
  __hip_bfloat16* g1b = (__hip_bfloat16*)wsb;                 // [NGRAPH*N2PAD] FC1 out
  wsb += (size_t)NGRAPH * N2PAD * sizeof(__hip_bfloat16);
  int* csr_src = (int*)wsb;      wsb += (size_t)EP * sizeof(int);
  int* counts = (int*)wsb;       wsb += (size_t)Nn * sizeof(int);
  int* row_start = (int*)wsb;    wsb += (size_t)(Nn + 1) * sizeof(int);
  int* cursor = (int*)wsb;       wsb += (size_t)Nn * sizeof(int);
  float* dinv = (float*)wsb;     wsb += (size_t)Nn * sizeof(float);
  size_t need = (size_t)(wsb - (char*)d_ws);
  if (need > ws_size) {
    fprintf(stderr, "kernel_launch: ws too small: need %zu have %zu\n", need, ws_size);
  }

  dim3 blk(256);

  // merged preprocessing: all casts + out=bias + counts=1
  int prep_total = Nn * K1 + N1PAD * K1 + NPAD * KPAD + N2PAD * K2PAD + 128 * N2PAD
                 + NGRAPH * 128 + Nn;
  prep_k<<<(prep_total + 255) / 256, 256, 0, stream>>>(x, Wl, Wr, W_gcn, W_fc1, W_fc2, b_fc2,
                                                       xbf, Wlrb, Wtb, Wfc1b, Wfc2b,
                                                       out, counts, Nn);

  // CSR by dst (self-loop slot first)
  count_k<<<512, 256, 0, stream>>>(dstv, E, counts);
  scan_k<<<1, 1024, 0, stream>>>(counts, row_start, Nn);
  node_init_k<<<(Nn + 255) / 256, 256, 0, stream>>>(row_start, cursor, csr_src, dinv, Nn);
  scatter_k<<<512, 256, 0, stream>>>(srcv, dstv, E, cursor, csr_src);

  // transform GEMM (bf16 MFMA, BK=64): xbf @ Wlrb^T -> xl (bufH) | xr (xrh), both fp16
  dim3 g1grid(N1PAD / 128, Nn / 128);
  gemm_f16_dual_k<<<g1grid, blk, 0, stream>>>((const unsigned short*)xbf,
                                              (const unsigned short*)Wlrb,
                                              bufH, xrh, Nn, N1, K1, K1);

  // GATv2 fused single-pass (packed fp16) -> h1bf (bf16, KPAD stride, padded cols zeroed)
  gatv2_fused_k<<<Nn, 320, 0, stream>>>(bufH, xrh, att, b_gat, row_start, csr_src, h1bf);

  // GCN matmul (bf16 MFMA, BK=64): h1bf @ Wtb^T -> h2 fp16 (bufH, xl dead), stride F
  dim3 g2grid(NPAD / 128, Nn / 128);
  gemm_f16o_k<<<g2grid, blk, 0, stream>>>((const unsigned short*)h1bf,
                                          (const unsigned short*)Wtb,
                                          bufH, Nn, F, KPAD, KPAD);

  // normalized aggregation (quad-per-lane fp16 gather) -> bf16 aggbf (aliases dead xr)
  gcn_agg_k<<<Nn, 256, 0, stream>>>(bufH, b_gcn, row_start, csr_src, dinv, aggbf);

  // pooling (bf16 in) -> bf16 pooled [NGRAPH x K2PAD], zero-padded
  pool_k<<<NGRAPH, 320, 0, stream>>>(aggbf, batch, pooledb, Nn);

  // FC1 (bf16 MFMA, BK=64): g1b = relu(pooled @ Wfc1b^T + b_fc1), bf16, padded to N2PAD
  dim3 fc1grid(N2PAD / 128, NGRAPH / 128);
  gemm_bf16_fc1_k<<<fc1grid, blk, 0, stream>>>((const unsigned short*)pooledb,
                                               (const unsigned short*)Wfc1b,
                                               b_fc1, g1b, NGRAPH, 1500, K2PAD, K2PAD);

  // FC2 (bf16 MFMA split-K): out += g1b @ Wfc2b^T (out pre-inited with b_fc2)
  dim3 fc2grid(1, NGRAPH / 128, 6);   // kchunk 256 -> 4 BK iters per block
  gemm_bf16_fc2_k<<<fc2grid, blk, 0, stream>>>((const unsigned short*)g1b,
                                               (const unsigned short*)Wfc2b,
                                               out, NGRAPH, 256);
}